// Round 1
// baseline (104.816 us; speedup 1.0000x reference)
//
#include <hip/hip_runtime.h>
#include <math.h>

#define N_NODES 8192
#define E_EDGES 262144
#define DIM 256
#define NEG_SLOPE 0.2f
#define ROW_CAP 128

typedef __attribute__((ext_vector_type(8))) short short8;
typedef __attribute__((ext_vector_type(4))) float f32x4;

// ---------------- workspace layout (bytes) ----------------
#define OFF_HB       0u          // 8192*256 bf16 = 4 MB
#define OFF_XB       4194304u    // 8192*256 bf16 = 4 MB
#define OFF_WT       8388608u    // 256*256 bf16 transposed = 128 KB
#define OFF_CURSOR   8519680u    // 8192 int (doubles as per-row count)
#define OFF_SV       8552448u    // 8192 f32
#define OFF_TV       8585216u    // 8192 f32
#define OFF_SALL     8617984u    // 256 f32
#define ZERO_BASE    OFF_CURSOR
#define ZERO_BYTES   99328u      // cursor+sv+tv+S_all (contiguous)
#define ZERO_VEC4    6208u
#define OFF_CSR      8620032u    // 8192*128 int = 4 MB
// total ~12.8 MB

__device__ __forceinline__ unsigned f2bf(float f) {
  unsigned u = __float_as_uint(f);
  u += 0x7fffu + ((u >> 16) & 1u);
  return u >> 16;
}

// ---------------- setup: x->bf16, W->bf16^T, zero scratch (one node) ----------------
// blocks [0,1024): x convert; [1024,1088): W^T; [1088,1113): zero
__global__ __launch_bounds__(256) void setup_kernel(const float* __restrict__ x,
                                                    const float* __restrict__ W,
                                                    unsigned short* __restrict__ xb,
                                                    unsigned short* __restrict__ wt,
                                                    float4* __restrict__ zero_p) {
  const int b = blockIdx.x;
  const int t = threadIdx.x;
  if (b < 1024) {                       // x convert: 2048 elems / block
    const int i = b * 2048 + t * 8;
    const float4 v0 = *(const float4*)(x + i);
    const float4 v1 = *(const float4*)(x + i + 4);
    uint4 o;
    o.x = f2bf(v0.x) | (f2bf(v0.y) << 16);
    o.y = f2bf(v0.z) | (f2bf(v0.w) << 16);
    o.z = f2bf(v1.x) | (f2bf(v1.y) << 16);
    o.w = f2bf(v1.z) | (f2bf(v1.w) << 16);
    *(uint4*)(xb + i) = o;
  } else if (b < 1088) {                // W transpose: Wt[n][k] = W[k][n]
    const int idx = (b - 1024) * 1024 + t * 4;
    const int n = idx >> 8;
    const int k = idx & 255;
    uint2 o;
    o.x = f2bf(W[(size_t)k * DIM + n]) | (f2bf(W[(size_t)(k + 1) * DIM + n]) << 16);
    o.y = f2bf(W[(size_t)(k + 2) * DIM + n]) | (f2bf(W[(size_t)(k + 3) * DIM + n]) << 16);
    *(uint2*)(wt + idx) = o;
  } else {                              // zero scratch
    const unsigned i = (b - 1088) * 256 + t;
    if (i < ZERO_VEC4) zero_p[i] = float4{0.f, 0.f, 0.f, 0.f};
  }
}

// ---------------- MFMA GEMM (blocks 0..255) + edge scatter (blocks 256..767) ----------------
// GEMM: h = xb @ Wt^T, bf16 in / fp32 acc, tile 128m x 64n, K pipelined with a
// double-buffered LDS + raw s_barrier: per K-step we do
//   [s_waitcnt vmcnt(0); s_barrier; issue next-tile global_load_lds; ds_read+MFMA]
// so the next tile's loads fly during the current tile's compute (one barrier/step,
// no post-compute drain). 48 KB LDS -> 3 blocks/CU, so scatter is 512 blocks x 2
// edges/thread: the full 768-block grid is co-resident in one scheduling round.
__global__ __launch_bounds__(256) void gemm_scatter_kernel(const unsigned short* __restrict__ xb,
                                                           const unsigned short* __restrict__ wt,
                                                           const float* __restrict__ a,
                                                           unsigned short* __restrict__ hb,
                                                           float* __restrict__ sv,
                                                           float* __restrict__ tv,
                                                           float* __restrict__ S_all,
                                                           const int* __restrict__ ei,
                                                           int* __restrict__ cursor,
                                                           int* __restrict__ csr) {
  const int bid = blockIdx.x;
  if (bid >= 256) {                     // ---- scatter: two edges per thread ----
    const int k0e = (bid - 256) * 256 + threadIdx.x;
#pragma unroll
    for (int h = 0; h < 2; ++h) {
      const int k = k0e + h * 131072;
      const int src = ei[k];
      const int tgt = ei[E_EDGES + k];
      const int pos = atomicAdd(&cursor[src], 1);
      if (pos < ROW_CAP) csr[src * ROW_CAP + pos] = tgt;
    }
    return;
  }
  __shared__ unsigned short Al[2][128 * 64];   // 2 x 16 KB, swizzled: [m][kv^(m&7)]
  __shared__ unsigned short Bl[2][64 * 64];    // 2 x 8 KB,  swizzled: [n][kv^(n&7)]
  const int bx = bid >> 2, by = bid & 3;
  const int m0 = bx * 128, n0 = by * 64;
  const int t = threadIdx.x;
  const int w = t >> 6, l = t & 63;
  const int q = l >> 4, l15 = l & 15;

  f32x4 acc[2][4] = {{{0.f,0.f,0.f,0.f},{0.f,0.f,0.f,0.f},{0.f,0.f,0.f,0.f},{0.f,0.f,0.f,0.f}},
                     {{0.f,0.f,0.f,0.f},{0.f,0.f,0.f,0.f},{0.f,0.f,0.f,0.f},{0.f,0.f,0.f,0.f}}};

  const int lrow = l >> 3;
  const int kvs = (l & 7) ^ lrow;       // pre-swizzled global k-chunk for linear LDS dest

  auto stage = [&](int ki, int buf) {
    const int k0 = ki * 64;
#pragma unroll
    for (int o = 0; o < 4; ++o) {
      const int op = w * 4 + o;
      const unsigned short* gp = xb + (size_t)(m0 + op * 8 + lrow) * DIM + k0 + kvs * 8;
      __builtin_amdgcn_global_load_lds((const __attribute__((address_space(1))) unsigned*)gp,
                                       (__attribute__((address_space(3))) unsigned*)(&Al[buf][op * 512]),
                                       16, 0, 0);
    }
#pragma unroll
    for (int o = 0; o < 2; ++o) {
      const int op = w * 2 + o;
      const unsigned short* gp = wt + (size_t)(n0 + op * 8 + lrow) * DIM + k0 + kvs * 8;
      __builtin_amdgcn_global_load_lds((const __attribute__((address_space(1))) unsigned*)gp,
                                       (__attribute__((address_space(3))) unsigned*)(&Bl[buf][op * 512]),
                                       16, 0, 0);
    }
  };

  stage(0, 0);
  int buf = 0;
  for (int ki = 0; ki < 4; ++ki) {
    // own stage(ki) loads are the only outstanding VMEM -> plain vmcnt(0) is exact.
    asm volatile("s_waitcnt vmcnt(0)" ::: "memory");
    __builtin_amdgcn_s_barrier();        // all waves' tile-ki data now in LDS
    if (ki < 3) stage(ki + 1, buf ^ 1);  // overlaps with compute below
#pragma unroll
    for (int s = 0; s < 2; ++s) {
      const int kv = s * 4 + q;
      short8 af[2], bf[4];
#pragma unroll
      for (int mi = 0; mi < 2; ++mi) {
        const int m = w * 32 + mi * 16 + l15;
        af[mi] = *(const short8*)(&Al[buf][m * 64 + ((kv ^ (m & 7)) * 8)]);
      }
#pragma unroll
      for (int nt = 0; nt < 4; ++nt) {
        const int n = nt * 16 + l15;
        bf[nt] = *(const short8*)(&Bl[buf][n * 64 + ((kv ^ (n & 7)) * 8)]);
      }
#pragma unroll
      for (int mi = 0; mi < 2; ++mi)
#pragma unroll
        for (int nt = 0; nt < 4; ++nt)
          acc[mi][nt] = __builtin_amdgcn_mfma_f32_16x16x32_bf16(af[mi], bf[nt], acc[mi][nt], 0, 0, 0);
    }
    buf ^= 1;
  }

  // ---- epilogue (registers only, no LDS -> no trailing barrier) ----
  float asv[4], atv[4];
#pragma unroll
  for (int nt = 0; nt < 4; ++nt) {
    const int n = n0 + nt * 16 + l15;
    asv[nt] = a[n];
    atv[nt] = a[DIM + n];
  }
#pragma unroll
  for (int mi = 0; mi < 2; ++mi)
#pragma unroll
    for (int r = 0; r < 4; ++r) {
      float sp = 0.f, tp = 0.f;
#pragma unroll
      for (int nt = 0; nt < 4; ++nt) {
        const float v = acc[mi][nt][r];
        sp += v * asv[nt];
        tp += v * atv[nt];
      }
#pragma unroll
      for (int off = 1; off < 16; off <<= 1) {
        sp += __shfl_xor(sp, off);
        tp += __shfl_xor(tp, off);
      }
      if (l15 == 0) {
        const int m = m0 + w * 32 + mi * 16 + q * 4 + r;
        atomicAdd(&sv[m], sp);
        atomicAdd(&tv[m], tp);
      }
    }
#pragma unroll
  for (int nt = 0; nt < 4; ++nt) {
    float cs = 0.f;
#pragma unroll
    for (int mi = 0; mi < 2; ++mi)
#pragma unroll
      for (int r = 0; r < 4; ++r) cs += acc[mi][nt][r];
    cs += __shfl_xor(cs, 16);
    cs += __shfl_xor(cs, 32);
    if (q == 0) atomicAdd(&S_all[n0 + nt * 16 + l15], cs);
  }
#pragma unroll
  for (int mi = 0; mi < 2; ++mi)
#pragma unroll
    for (int r = 0; r < 4; ++r) {
      const int m = m0 + w * 32 + mi * 16 + q * 4 + r;
#pragma unroll
      for (int nt = 0; nt < 4; ++nt)
        hb[(size_t)m * DIM + n0 + nt * 16 + l15] = (unsigned short)f2bf(acc[mi][nt][r]);
    }
}

// ---------------- per-row accumulate + finalize (dedup via LDS bitmap) ----------------
// 1 wave per row; lane l owns dims [4l,4l+4).
// Broadcast of (weight, target) uses v_readlane -> SGPR: the hb gather becomes an
// SGPR-based (saddr) load and the weight an SGPR FMA operand (no ds_bpermute).
// Z is accumulated lane-parallel in phase 1 and wave-reduced once at the end.
// bm[w] is wave-private and same-wave LDS ops execute in order -> no barrier needed.
__global__ __launch_bounds__(256) void row_kernel(const unsigned short* __restrict__ hb,
                                                  const float* __restrict__ sv,
                                                  const float* __restrict__ tv,
                                                  const float* __restrict__ S_all,
                                                  const int* __restrict__ cursor,
                                                  const int* __restrict__ csr,
                                                  float* __restrict__ out) {
  __shared__ unsigned bm[4][256];           // 8192-bit dedup bitmap per wave
  const int w = threadIdx.x >> 6;
  const int lane = threadIdx.x & 63;
  const int row = blockIdx.x * 4 + w;
#pragma unroll
  for (int i = lane; i < 256; i += 64) bm[w][i] = 0u;

  const int n_total = min(cursor[row], ROW_CAP);
  const float srow = sv[row];

  float4 acc = {0.f, 0.f, 0.f, 0.f};
  float zacc = 0.f;

  for (int e0 = 0; e0 < n_total; e0 += 64) {
    const int cn = min(64, n_total - e0);
    float wgt = 0.f;
    int tg = 0;
    if (lane < cn) {
      tg = csr[row * ROW_CAP + e0 + lane];
      const unsigned msk = 1u << (tg & 31);
      const unsigned old = atomicOr(&bm[w][tg >> 5], msk);
      if (!(old & msk)) {
        float ev = srow + tv[tg];
        ev = (ev > 0.f) ? ev : NEG_SLOPE * ev;
        wgt = expm1f(ev);
      }
    }
    zacc += wgt;                           // lanes >= cn / dup lanes carry 0
    // unroll-8 gather groups; padded slots have wgt=0 / tg=0 so they are no-ops
    for (int j = 0; j < cn; j += 8) {
#pragma unroll
      for (int u = 0; u < 8; ++u) {
        const int tj = __builtin_amdgcn_readlane(tg, j + u);
        const float wj = __uint_as_float(
            (unsigned)__builtin_amdgcn_readlane((int)__float_as_uint(wgt), j + u));
        const uint2 p = *(const uint2*)(hb + (size_t)tj * DIM + (lane << 2));
        acc.x += wj * __uint_as_float(p.x << 16);
        acc.y += wj * __uint_as_float(p.x & 0xffff0000u);
        acc.z += wj * __uint_as_float(p.y << 16);
        acc.w += wj * __uint_as_float(p.y & 0xffff0000u);
      }
    }
  }

#pragma unroll
  for (int off = 1; off < 64; off <<= 1) zacc += __shfl_xor(zacc, off);

  const float4 sa = *(const float4*)(S_all + (lane << 2));
  const float inv = 1.0f / ((float)N_NODES + zacc);
  float4 o;
  o.x = (sa.x + acc.x) * inv;
  o.y = (sa.y + acc.y) * inv;
  o.z = (sa.z + acc.z) * inv;
  o.w = (sa.w + acc.w) * inv;
  *(float4*)(out + (size_t)row * DIM + (lane << 2)) = o;
}

extern "C" void kernel_launch(void* const* d_in, const int* in_sizes, int n_in,
                              void* d_out, int out_size, void* d_ws, size_t ws_size,
                              hipStream_t stream) {
  const float* x = (const float*)d_in[0];
  const int* ei = (const int*)d_in[1];
  const float* W = (const float*)d_in[2];
  const float* a = (const float*)d_in[3];
  float* out = (float*)d_out;

  unsigned char* ws = (unsigned char*)d_ws;
  unsigned short* hb = (unsigned short*)(ws + OFF_HB);
  unsigned short* xb = (unsigned short*)(ws + OFF_XB);
  unsigned short* wt = (unsigned short*)(ws + OFF_WT);
  int* cursor = (int*)(ws + OFF_CURSOR);
  float* sv = (float*)(ws + OFF_SV);
  float* tv = (float*)(ws + OFF_TV);
  float* S_all = (float*)(ws + OFF_SALL);
  int* csr = (int*)(ws + OFF_CSR);

  setup_kernel<<<1113, 256, 0, stream>>>(x, W, xb, wt, (float4*)(ws + ZERO_BASE));
  gemm_scatter_kernel<<<768, 256, 0, stream>>>(xb, wt, a, hb, sv, tv, S_all, ei, cursor, csr);
  row_kernel<<<N_NODES / 4, 256, 0, stream>>>(hb, sv, tv, S_all, cursor, csr, out);
}

// Round 2
// 104.469 us; speedup vs baseline: 1.0033x; 1.0033x over previous
//
#include <hip/hip_runtime.h>
#include <math.h>

#define N_NODES 8192
#define E_EDGES 262144
#define DIM 256
#define NEG_SLOPE 0.2f
#define ROW_CAP 128

typedef __attribute__((ext_vector_type(8))) short short8;
typedef __attribute__((ext_vector_type(4))) float f32x4;

// ---------------- workspace layout (bytes) ----------------
#define OFF_HB       0u          // 8192*256 bf16 = 4 MB
#define OFF_XB       4194304u    // (unused now, kept for layout stability)
#define OFF_WT       8388608u    // 256*256 bf16 transposed = 128 KB
#define OFF_CURSOR   8519680u    // 8192 int (doubles as per-row count)
#define OFF_SV       8552448u    // 8192 f32
#define OFF_TV       8585216u    // 8192 f32
#define OFF_SALL     8617984u    // 256 f32
#define ZERO_BASE    OFF_CURSOR
#define ZERO_BYTES   99328u      // cursor+sv+tv+S_all (contiguous)
#define ZERO_VEC4    6208u
#define OFF_CSR      8620032u    // 8192*128 int = 4 MB
// total ~12.8 MB

__device__ __forceinline__ unsigned f2bf(float f) {
  unsigned u = __float_as_uint(f);
  u += 0x7fffu + ((u >> 16) & 1u);
  return u >> 16;
}

// ---------------- setup: W->bf16^T + zero scratch ----------------
// blocks [0,64): W^T; [64,89): zero.  x is no longer pre-converted — the GEMM
// reads x f32 directly and converts to bf16 fragments in registers.
__global__ __launch_bounds__(256) void setup_kernel(const float* __restrict__ W,
                                                    unsigned short* __restrict__ wt,
                                                    float4* __restrict__ zero_p) {
  const int b = blockIdx.x;
  const int t = threadIdx.x;
  if (b < 64) {                         // W transpose: Wt[n][k] = W[k][n]
    const int idx = b * 1024 + t * 4;
    const int n = idx >> 8;
    const int k = idx & 255;
    uint2 o;
    o.x = f2bf(W[(size_t)k * DIM + n]) | (f2bf(W[(size_t)(k + 1) * DIM + n]) << 16);
    o.y = f2bf(W[(size_t)(k + 2) * DIM + n]) | (f2bf(W[(size_t)(k + 3) * DIM + n]) << 16);
    *(uint2*)(wt + idx) = o;
  } else {                              // zero scratch
    const unsigned i = (b - 64) * 256 + t;
    if (i < ZERO_VEC4) zero_p[i] = float4{0.f, 0.f, 0.f, 0.f};
  }
}

// ---------------- MFMA GEMM (blocks 0..255) + edge scatter (blocks 256..767) ----------------
// GEMM: h = x @ W (bf16 MFMA, fp32 acc), tile 128m x 64n.
// A path: x f32 -> registers -> bf16 fragments (all 8 K-steps resident in VGPRs);
// A never touches LDS. K-loop stages only B (wt, bf16) via global_load_lds into a
// 2x8KB double buffer: [vmcnt(0); s_barrier; stage B(ki+1); ds_read B; MFMA].
// 16 KB LDS -> scatter blocks co-resident at high occupancy.
__global__ __launch_bounds__(256) void gemm_scatter_kernel(const float* __restrict__ x,
                                                           const unsigned short* __restrict__ wt,
                                                           const float* __restrict__ a,
                                                           unsigned short* __restrict__ hb,
                                                           float* __restrict__ sv,
                                                           float* __restrict__ tv,
                                                           float* __restrict__ S_all,
                                                           const int* __restrict__ ei,
                                                           int* __restrict__ cursor,
                                                           int* __restrict__ csr) {
  const int bid = blockIdx.x;
  if (bid >= 256) {                     // ---- scatter: two edges per thread ----
    const int k0e = (bid - 256) * 256 + threadIdx.x;
#pragma unroll
    for (int h = 0; h < 2; ++h) {
      const int k = k0e + h * 131072;
      const int src = ei[k];
      const int tgt = ei[E_EDGES + k];
      const int pos = atomicAdd(&cursor[src], 1);
      if (pos < ROW_CAP) csr[src * ROW_CAP + pos] = tgt;
    }
    return;
  }
  __shared__ unsigned short Bl[2][64 * 64];    // 2 x 8 KB, swizzled: [n][kv^(n&7)]
  const int bx = bid >> 2, by = bid & 3;
  const int m0 = bx * 128, n0 = by * 64;
  const int t = threadIdx.x;
  const int w = t >> 6, l = t & 63;
  const int q = l >> 4, l15 = l & 15;

  const int lrow = l >> 3;
  const int kvs = (l & 7) ^ lrow;       // pre-swizzled global k-chunk for linear LDS dest

  auto stageB = [&](int ki, int buf) {
    const int k0 = ki * 64;
#pragma unroll
    for (int o = 0; o < 2; ++o) {
      const int op = w * 2 + o;
      const unsigned short* gp = wt + (size_t)(n0 + op * 8 + lrow) * DIM + k0 + kvs * 8;
      __builtin_amdgcn_global_load_lds((const __attribute__((address_space(1))) unsigned*)gp,
                                       (__attribute__((address_space(3))) unsigned*)(&Bl[buf][op * 512]),
                                       16, 0, 0);
    }
  };

  stageB(0, 0);                          // B tile 0 in flight under the A load/convert

  // ---- A: x f32 -> bf16 MFMA fragments in registers, all K ----
  // frag (mi, ks): lane holds x[m0 + w*32 + mi*16 + l15][ks*32 + q*8 + j], j=0..7
  short8 afr[2][8];
#pragma unroll
  for (int mi = 0; mi < 2; ++mi) {
    const float* rp = x + (size_t)(m0 + w * 32 + mi * 16 + l15) * DIM + q * 8;
#pragma unroll
    for (int ks = 0; ks < 8; ++ks) {
      const float4 u0 = *(const float4*)(rp + ks * 32);
      const float4 u1 = *(const float4*)(rp + ks * 32 + 4);
      short8 f;
      f[0] = (short)f2bf(u0.x); f[1] = (short)f2bf(u0.y);
      f[2] = (short)f2bf(u0.z); f[3] = (short)f2bf(u0.w);
      f[4] = (short)f2bf(u1.x); f[5] = (short)f2bf(u1.y);
      f[6] = (short)f2bf(u1.z); f[7] = (short)f2bf(u1.w);
      afr[mi][ks] = f;
    }
  }

  f32x4 acc[2][4] = {{{0.f,0.f,0.f,0.f},{0.f,0.f,0.f,0.f},{0.f,0.f,0.f,0.f},{0.f,0.f,0.f,0.f}},
                     {{0.f,0.f,0.f,0.f},{0.f,0.f,0.f,0.f},{0.f,0.f,0.f,0.f},{0.f,0.f,0.f,0.f}}};

  int buf = 0;
  for (int ki = 0; ki < 4; ++ki) {
    // outstanding VMEM here = this tile's stageB (A loads drained by data deps)
    asm volatile("s_waitcnt vmcnt(0)" ::: "memory");
    __builtin_amdgcn_s_barrier();        // all waves' B tile ki now in LDS
    if (ki < 3) stageB(ki + 1, buf ^ 1); // overlaps with compute below
#pragma unroll
    for (int s = 0; s < 2; ++s) {
      const int kv = s * 4 + q;
      short8 bf[4];
#pragma unroll
      for (int nt = 0; nt < 4; ++nt) {
        const int n = nt * 16 + l15;
        bf[nt] = *(const short8*)(&Bl[buf][n * 64 + ((kv ^ (n & 7)) * 8)]);
      }
#pragma unroll
      for (int mi = 0; mi < 2; ++mi)
#pragma unroll
        for (int nt = 0; nt < 4; ++nt)
          acc[mi][nt] = __builtin_amdgcn_mfma_f32_16x16x32_bf16(afr[mi][ki * 2 + s], bf[nt],
                                                                acc[mi][nt], 0, 0, 0);
    }
    buf ^= 1;
  }

  // ---- epilogue (registers only) ----
  float asv[4], atv[4];
#pragma unroll
  for (int nt = 0; nt < 4; ++nt) {
    const int n = n0 + nt * 16 + l15;
    asv[nt] = a[n];
    atv[nt] = a[DIM + n];
  }
#pragma unroll
  for (int mi = 0; mi < 2; ++mi)
#pragma unroll
    for (int r = 0; r < 4; ++r) {
      float sp = 0.f, tp = 0.f;
#pragma unroll
      for (int nt = 0; nt < 4; ++nt) {
        const float v = acc[mi][nt][r];
        sp += v * asv[nt];
        tp += v * atv[nt];
      }
#pragma unroll
      for (int off = 1; off < 16; off <<= 1) {
        sp += __shfl_xor(sp, off);
        tp += __shfl_xor(tp, off);
      }
      if (l15 == 0) {
        const int m = m0 + w * 32 + mi * 16 + q * 4 + r;
        atomicAdd(&sv[m], sp);
        atomicAdd(&tv[m], tp);
      }
    }
#pragma unroll
  for (int nt = 0; nt < 4; ++nt) {
    float cs = 0.f;
#pragma unroll
    for (int mi = 0; mi < 2; ++mi)
#pragma unroll
      for (int r = 0; r < 4; ++r) cs += acc[mi][nt][r];
    cs += __shfl_xor(cs, 16);
    cs += __shfl_xor(cs, 32);
    if (q == 0) atomicAdd(&S_all[n0 + nt * 16 + l15], cs);
  }
#pragma unroll
  for (int mi = 0; mi < 2; ++mi)
#pragma unroll
    for (int r = 0; r < 4; ++r) {
      const int m = m0 + w * 32 + mi * 16 + q * 4 + r;
#pragma unroll
      for (int nt = 0; nt < 4; ++nt)
        hb[(size_t)m * DIM + n0 + nt * 16 + l15] = (unsigned short)f2bf(acc[mi][nt][r]);
    }
}

// ---------------- per-row accumulate + finalize (dedup via LDS bitmap) ----------------
// 1 wave per row; lane l owns dims [4l,4l+4).
// Broadcast of (weight, target) via v_readlane -> SGPR: saddr gathers, SGPR FMA operand.
// Z accumulated lane-parallel, one wave reduction at the end.
// bm[w] is wave-private; same-wave LDS ops are ordered -> no barrier needed.
__global__ __launch_bounds__(256) void row_kernel(const unsigned short* __restrict__ hb,
                                                  const float* __restrict__ sv,
                                                  const float* __restrict__ tv,
                                                  const float* __restrict__ S_all,
                                                  const int* __restrict__ cursor,
                                                  const int* __restrict__ csr,
                                                  float* __restrict__ out) {
  __shared__ unsigned bm[4][256];           // 8192-bit dedup bitmap per wave
  const int w = threadIdx.x >> 6;
  const int lane = threadIdx.x & 63;
  const int row = blockIdx.x * 4 + w;
#pragma unroll
  for (int i = lane; i < 256; i += 64) bm[w][i] = 0u;

  const int n_total = min(cursor[row], ROW_CAP);
  const float srow = sv[row];

  float4 acc = {0.f, 0.f, 0.f, 0.f};
  float zacc = 0.f;

  for (int e0 = 0; e0 < n_total; e0 += 64) {
    const int cn = min(64, n_total - e0);
    float wgt = 0.f;
    int tg = 0;
    if (lane < cn) {
      tg = csr[row * ROW_CAP + e0 + lane];
      const unsigned msk = 1u << (tg & 31);
      const unsigned old = atomicOr(&bm[w][tg >> 5], msk);
      if (!(old & msk)) {
        float ev = srow + tv[tg];
        ev = (ev > 0.f) ? ev : NEG_SLOPE * ev;
        wgt = expm1f(ev);
      }
    }
    zacc += wgt;                           // lanes >= cn / dup lanes carry 0
    // unroll-8 gather groups; padded slots have wgt=0 / tg=0 so they are no-ops
    for (int j = 0; j < cn; j += 8) {
#pragma unroll
      for (int u = 0; u < 8; ++u) {
        const int tj = __builtin_amdgcn_readlane(tg, j + u);
        const float wj = __uint_as_float(
            (unsigned)__builtin_amdgcn_readlane((int)__float_as_uint(wgt), j + u));
        const uint2 p = *(const uint2*)(hb + (size_t)tj * DIM + (lane << 2));
        acc.x += wj * __uint_as_float(p.x << 16);
        acc.y += wj * __uint_as_float(p.x & 0xffff0000u);
        acc.z += wj * __uint_as_float(p.y << 16);
        acc.w += wj * __uint_as_float(p.y & 0xffff0000u);
      }
    }
  }

#pragma unroll
  for (int off = 1; off < 64; off <<= 1) zacc += __shfl_xor(zacc, off);

  const float4 sa = *(const float4*)(S_all + (lane << 2));
  const float inv = 1.0f / ((float)N_NODES + zacc);
  float4 o;
  o.x = (sa.x + acc.x) * inv;
  o.y = (sa.y + acc.y) * inv;
  o.z = (sa.z + acc.z) * inv;
  o.w = (sa.w + acc.w) * inv;
  *(float4*)(out + (size_t)row * DIM + (lane << 2)) = o;
}

extern "C" void kernel_launch(void* const* d_in, const int* in_sizes, int n_in,
                              void* d_out, int out_size, void* d_ws, size_t ws_size,
                              hipStream_t stream) {
  const float* x = (const float*)d_in[0];
  const int* ei = (const int*)d_in[1];
  const float* W = (const float*)d_in[2];
  const float* a = (const float*)d_in[3];
  float* out = (float*)d_out;

  unsigned char* ws = (unsigned char*)d_ws;
  unsigned short* hb = (unsigned short*)(ws + OFF_HB);
  unsigned short* wt = (unsigned short*)(ws + OFF_WT);
  int* cursor = (int*)(ws + OFF_CURSOR);
  float* sv = (float*)(ws + OFF_SV);
  float* tv = (float*)(ws + OFF_TV);
  float* S_all = (float*)(ws + OFF_SALL);
  int* csr = (int*)(ws + OFF_CSR);

  setup_kernel<<<89, 256, 0, stream>>>(W, wt, (float4*)(ws + ZERO_BASE));
  gemm_scatter_kernel<<<768, 256, 0, stream>>>(x, wt, a, hb, sv, tv, S_all, ei, cursor, csr);
  row_kernel<<<N_NODES / 4, 256, 0, stream>>>(hb, sv, tv, S_all, cursor, csr, out);
}